// Round 1
// 936.267 us; speedup vs baseline: 1.0503x; 1.0503x over previous
//
#include <hip/hip_runtime.h>
#include <hip/hip_bf16.h>

// Problem constants: B=4, N=2048, D=1024, H=16, dh=64. All I/O fp32.
#define SEQ   2048
#define DIM   1024
#define HEADS 16
#define DH    64
#define MROWS 8192            // B*N
#define K3    3072            // 3*D
#define NEGV  (-32767.0f)     // -2^15+1, matches reference mask constant
#define SCALE 8.0f            // sqrt(dh) — reference MULTIPLIES by sqrt(d)

typedef __attribute__((ext_vector_type(8))) short bf16x8;
typedef __attribute__((ext_vector_type(4))) float f32x4;

// bf16 round-to-nearest-even via bit ops (finite inputs only)
__device__ __forceinline__ short f2bf(float x) {
  union { float f; unsigned u; } v; v.f = x;
  unsigned r = v.u + 0x7FFF + ((v.u >> 16) & 1);
  return (short)(r >> 16);
}
__device__ __forceinline__ float bf2f(short s) {
  union { float f; unsigned u; } v; v.u = ((unsigned)(unsigned short)s) << 16;
  return v.f;
}
__device__ __forceinline__ void split1(float x, short& h, short& l) {
  h = f2bf(x);
  l = f2bf(x - bf2f(h));
}
__device__ __forceinline__ void cvt_split8(const float4 a, const float4 b,
                                           bf16x8& hi, bf16x8& lo) {
  const float f[8] = {a.x, a.y, a.z, a.w, b.x, b.y, b.z, b.w};
#pragma unroll
  for (int i = 0; i < 8; i++) {
    short h, l; split1(f[i], h, l);
    hi[i] = h; lo[i] = l;
  }
}

// async global->LDS, 16B per lane. LDS dest is wave-uniform base; HW writes
// lane l at base + l*16 bytes. Global src is per-lane.
__device__ __forceinline__ void glds16(const void* g, void* l) {
  __builtin_amdgcn_global_load_lds(
      (const __attribute__((address_space(1))) void*)g,
      (__attribute__((address_space(3))) void*)l, 16, 0, 0);
}

// XOR-swizzled LDS index (shorts) for 64-col row-major tiles: 8-short (16B)
// blocks permuted by row&7 -> ds_read_b128-able fragments, spread banks.
__device__ __forceinline__ int sw(int row, int col) {
  return row * 64 + ((((col >> 3) ^ row) & 7) << 3) + (col & 7);
}

// ---------------------------------------------------------------------------
// Prep kernels: one-time fp32 -> bf16 hi/lo RNE split (identical values to
// the old in-loop cvt_split8). Removes ~45% VALUBusy from the GEMM loop.
// ---------------------------------------------------------------------------
__global__ __launch_bounds__(256) void prep_x(
    const float* __restrict__ q, const float* __restrict__ k,
    const float* __restrict__ v,
    short* __restrict__ ah, short* __restrict__ al)  // (8192, 3072) bf16 each
{
  const int n = MROWS * (K3 / 4);                    // float4 work items
  for (int i = blockIdx.x * 256 + threadIdx.x; i < n; i += gridDim.x * 256) {
    const int r  = i / 768;                          // 3072/4 cols per row
    const int c4 = i - r * 768;
    const float* src = (c4 < 256) ? q : ((c4 < 512) ? k : v);
    const int cc = c4 & 255;
    const float4 f = *(const float4*)(src + ((size_t)r * 256 + cc) * 4);
    const float fa[4] = {f.x, f.y, f.z, f.w};
    short hi[4], lo[4];
#pragma unroll
    for (int e = 0; e < 4; ++e) split1(fa[e], hi[e], lo[e]);
    const size_t o = (size_t)r * K3 + c4 * 4;
    *(short4*)(ah + o) = make_short4(hi[0], hi[1], hi[2], hi[3]);
    *(short4*)(al + o) = make_short4(lo[0], lo[1], lo[2], lo[3]);
  }
}

__global__ __launch_bounds__(256) void prep_w(
    const float* __restrict__ w,                     // (3072,3072) fp32
    short* __restrict__ bh, short* __restrict__ bl)  // bf16 each
{
  const int n = (K3 * K3) / 4;
  for (int i = blockIdx.x * 256 + threadIdx.x; i < n; i += gridDim.x * 256) {
    const float4 f = ((const float4*)w)[i];
    const float fa[4] = {f.x, f.y, f.z, f.w};
    short hi[4], lo[4];
#pragma unroll
    for (int e = 0; e < 4; ++e) split1(fa[e], hi[e], lo[e]);
    ((short4*)bh)[i] = make_short4(hi[0], hi[1], hi[2], hi[3]);
    ((short4*)bl)[i] = make_short4(lo[0], lo[1], lo[2], lo[3]);
  }
}

// ---------------------------------------------------------------------------
// Kernel 1a (prep path): qkv GEMM from pre-split bf16 operands.
// m97 structure: global_load_lds(16B) staging -> ds_read_b128 -> MFMA.
// Q/K output cols: 3-MFMA compensated (hh + hl + lh); V cols 1-pass.
// Output: qkv as bf16 hi/lo planes (lo only for q,k cols).
// ---------------------------------------------------------------------------
__global__ __launch_bounds__(256) void qkv_gemm_pre(
    const short* __restrict__ Ah, const short* __restrict__ Al,
    const short* __restrict__ Bh, const short* __restrict__ Bl,
    const float* __restrict__ bqkv,
    short* __restrict__ qh, short* __restrict__ ql)
{
  __shared__ short Ash[128 * 32];
  __shared__ short Asl[128 * 32];
  __shared__ short Bsh[128 * 32];
  __shared__ short Bsl[128 * 32];

  const int t    = threadIdx.x;
  const int lane = t & 63;
  const int wv   = t >> 6;

  // XCD-chunked bijective swizzle: nwg = 24*64 = 1536 = 8*192
  int wg = blockIdx.y * 24 + blockIdx.x;
  wg = (wg & 7) * 192 + (wg >> 3);
  const int Mb = (wg / 24) * 128;
  const int Nb = (wg % 24) * 128;

  const bool prec = (Nb < 2 * DIM);   // q,k columns need compensation
  const int wr   = (wv >> 1) * 64;
  const int wc   = (wv & 1) * 64;
  const int l15  = lane & 15;
  const int lq   = lane >> 4;
  const int grow = lane >> 2;         // staging: row within 16-row issue
  const int gcol = (lane & 3) * 8;    // staging: col (shorts)

  f32x4 acc[4][4];
#pragma unroll
  for (int i = 0; i < 4; i++)
#pragma unroll
    for (int j = 0; j < 4; j++) acc[i][j] = (f32x4){0.f, 0.f, 0.f, 0.f};

  for (int k0 = 0; k0 < K3; k0 += 32) {
    __syncthreads();                  // prev iteration's fragment reads done
#pragma unroll
    for (int it = 0; it < 2; ++it) {
      const int r0 = wv * 32 + it * 16;            // wave-uniform
      const size_t ga = (size_t)(Mb + r0 + grow) * K3 + k0 + gcol;
      const size_t gb = (size_t)(Nb + r0 + grow) * K3 + k0 + gcol;
      glds16(Ah + ga, Ash + r0 * 32);
      glds16(Bh + gb, Bsh + r0 * 32);
      if (prec) {
        glds16(Al + ga, Asl + r0 * 32);
        glds16(Bl + gb, Bsl + r0 * 32);
      }
    }
    __syncthreads();                  // vmcnt drained by compiler before barrier

    bf16x8 afh[4], bfh[4];
#pragma unroll
    for (int i = 0; i < 4; i++)
      afh[i] = *(const bf16x8*)(Ash + (wr + i * 16 + l15) * 32 + lq * 8);
#pragma unroll
    for (int j = 0; j < 4; j++)
      bfh[j] = *(const bf16x8*)(Bsh + (wc + j * 16 + l15) * 32 + lq * 8);
#pragma unroll
    for (int i = 0; i < 4; i++)
#pragma unroll
      for (int j = 0; j < 4; j++)
        acc[i][j] = __builtin_amdgcn_mfma_f32_16x16x32_bf16(afh[i], bfh[j], acc[i][j], 0, 0, 0);

    if (prec) {
      bf16x8 afl[4], bfl[4];
#pragma unroll
      for (int i = 0; i < 4; i++)
        afl[i] = *(const bf16x8*)(Asl + (wr + i * 16 + l15) * 32 + lq * 8);
#pragma unroll
      for (int j = 0; j < 4; j++)
        bfl[j] = *(const bf16x8*)(Bsl + (wc + j * 16 + l15) * 32 + lq * 8);
#pragma unroll
      for (int i = 0; i < 4; i++)
#pragma unroll
        for (int j = 0; j < 4; j++) {
          acc[i][j] = __builtin_amdgcn_mfma_f32_16x16x32_bf16(afh[i], bfl[j], acc[i][j], 0, 0, 0);
          acc[i][j] = __builtin_amdgcn_mfma_f32_16x16x32_bf16(afl[i], bfh[j], acc[i][j], 0, 0, 0);
        }
    }
  }

#pragma unroll
  for (int j = 0; j < 4; j++) {
    const int col = Nb + wc + j * 16 + l15;
    const float bias = bqkv[col];
#pragma unroll
    for (int i = 0; i < 4; i++) {
#pragma unroll
      for (int r = 0; r < 4; r++) {
        const int row = Mb + wr + i * 16 + lq * 4 + r;
        const float xv = acc[i][j][r] + bias;
        const short hh = f2bf(xv);
        qh[(size_t)row * K3 + col] = hh;
        if (prec) ql[(size_t)row * K3 + col] = f2bf(xv - bf2f(hh));
      }
    }
  }
}

// ---------------------------------------------------------------------------
// Kernel 1b (fallback, ws too small for prep): in-loop cvt (proven structure),
// epilogue changed to bf16 hi/lo output.
// ---------------------------------------------------------------------------
__global__ __launch_bounds__(256) void qkv_gemm_fly(
    const float* __restrict__ q,
    const float* __restrict__ k,
    const float* __restrict__ v,
    const float* __restrict__ wqkv,
    const float* __restrict__ bqkv,
    short* __restrict__ qh, short* __restrict__ ql)
{
  __shared__ short Ash[128 * 32];
  __shared__ short Asl[128 * 32];
  __shared__ short Bsh[128 * 32];
  __shared__ short Bsl[128 * 32];

  const int t    = threadIdx.x;
  const int lane = t & 63;
  const int wv   = t >> 6;
  const int Mb   = blockIdx.y * 128;
  const int Nb   = blockIdx.x * 128;
  const bool prec = (Nb < 2 * DIM);
  const int wr   = (wv >> 1) * 64;
  const int wc   = (wv & 1) * 64;
  const int l15  = lane & 15;
  const int lq   = lane >> 4;
  const int srow = wv * 16 + (lane >> 2);
  const int scol = (lane & 3) * 8;

  f32x4 acc[4][4];
#pragma unroll
  for (int i = 0; i < 4; i++)
#pragma unroll
    for (int j = 0; j < 4; j++) acc[i][j] = (f32x4){0.f, 0.f, 0.f, 0.f};

  for (int k0 = 0; k0 < K3; k0 += 32) {
    const float* src = (k0 < DIM) ? q : ((k0 < 2 * DIM) ? k : v);
    const int koff = (k0 & (DIM - 1)) + scol;

    bf16x8 ah[2], al[2], bh[2], bl[2];
#pragma unroll
    for (int it = 0; it < 2; ++it) {
      const float* ap = src + (size_t)(Mb + it * 64 + srow) * DIM + koff;
      cvt_split8(*(const float4*)(ap), *(const float4*)(ap + 4), ah[it], al[it]);
      const float* bp = wqkv + (size_t)(Nb + it * 64 + srow) * K3 + k0 + scol;
      cvt_split8(*(const float4*)(bp), *(const float4*)(bp + 4), bh[it], bl[it]);
    }
    __syncthreads();
#pragma unroll
    for (int it = 0; it < 2; ++it) {
      *(bf16x8*)(Ash + (it * 64 + srow) * 32 + scol) = ah[it];
      *(bf16x8*)(Bsh + (it * 64 + srow) * 32 + scol) = bh[it];
      if (prec) {
        *(bf16x8*)(Asl + (it * 64 + srow) * 32 + scol) = al[it];
        *(bf16x8*)(Bsl + (it * 64 + srow) * 32 + scol) = bl[it];
      }
    }
    __syncthreads();

    bf16x8 afh[4], bfh[4];
#pragma unroll
    for (int i = 0; i < 4; i++)
      afh[i] = *(const bf16x8*)(Ash + (wr + i * 16 + l15) * 32 + lq * 8);
#pragma unroll
    for (int j = 0; j < 4; j++)
      bfh[j] = *(const bf16x8*)(Bsh + (wc + j * 16 + l15) * 32 + lq * 8);
#pragma unroll
    for (int i = 0; i < 4; i++)
#pragma unroll
      for (int j = 0; j < 4; j++)
        acc[i][j] = __builtin_amdgcn_mfma_f32_16x16x32_bf16(afh[i], bfh[j], acc[i][j], 0, 0, 0);

    if (prec) {
      bf16x8 afl[4], bfl[4];
#pragma unroll
      for (int i = 0; i < 4; i++)
        afl[i] = *(const bf16x8*)(Asl + (wr + i * 16 + l15) * 32 + lq * 8);
#pragma unroll
      for (int j = 0; j < 4; j++)
        bfl[j] = *(const bf16x8*)(Bsl + (wc + j * 16 + l15) * 32 + lq * 8);
#pragma unroll
      for (int i = 0; i < 4; i++)
#pragma unroll
        for (int j = 0; j < 4; j++) {
          acc[i][j] = __builtin_amdgcn_mfma_f32_16x16x32_bf16(afh[i], bfl[j], acc[i][j], 0, 0, 0);
          acc[i][j] = __builtin_amdgcn_mfma_f32_16x16x32_bf16(afl[i], bfh[j], acc[i][j], 0, 0, 0);
        }
    }
  }

#pragma unroll
  for (int j = 0; j < 4; j++) {
    const int col = Nb + wc + j * 16 + l15;
    const float bias = bqkv[col];
#pragma unroll
    for (int i = 0; i < 4; i++) {
#pragma unroll
      for (int r = 0; r < 4; r++) {
        const int row = Mb + wr + i * 16 + lq * 4 + r;
        const float xv = acc[i][j][r] + bias;
        const short hh = f2bf(xv);
        qh[(size_t)row * K3 + col] = hh;
        if (prec) ql[(size_t)row * K3 + col] = f2bf(xv - bf2f(hh));
      }
    }
  }
}

// ---------------------------------------------------------------------------
// Kernel 2: MFMA flash attention, now reading bf16 hi/lo qkv planes directly.
// - Q A-fragments: per-lane 16B loads straight from global (no LDS, no cvt).
// - K hi/lo: global_load_lds with pre-swizzled global source (LDS dest linear
//   in lane order; sw() permutation folded into the source column block).
// - V: bf16 copy + transpose scatter into swizzled Vt.
// Softmax / P round-trip / PV identical to the proven version.
// ---------------------------------------------------------------------------
__global__ __launch_bounds__(256) void attn_fwd(
    const short* __restrict__ qkvh,         // (8192, 3072) bf16 hi
    const short* __restrict__ qkvl,         // (8192, 3072) bf16 lo (q,k cols)
    __hip_bfloat16* __restrict__ attno)     // (8192, 1024) bf16
{
  __shared__ short Kh[4096], Kl[4096], Vt[4096];
  __shared__ short Ps[4][1024];             // per-wave 16x64 P tile

  const int bx = blockIdx.x;
  const int qt = 31 - (bx & 31);            // heavy q-tiles dispatch first
  const int h  = (bx >> 5) & 15;
  const int b  = bx >> 9;
  const int qb = qt * 64;

  const int t    = threadIdx.x;
  const int lane = t & 63;
  const int wv   = t >> 6;
  const int l15  = lane & 15;
  const int quad = lane >> 4;
  const size_t rowBase = (size_t)b * SEQ;

  // Q A-fragments: A[m=l15][k=ks*32+quad*8+j], rows qb + 16*wv + l15
  bf16x8 qah[2], qal[2];
  {
    const size_t qoff = (rowBase + qb + 16 * wv + l15) * K3 + h * DH;
#pragma unroll
    for (int ks = 0; ks < 2; ++ks) {
      qah[ks] = *(const bf16x8*)(qkvh + qoff + ks * 32 + quad * 8);
      qal[ks] = *(const bf16x8*)(qkvl + qoff + ks * 32 + quad * 8);
    }
  }

  float m_i[4], l_i[4];
  f32x4 O[4];
#pragma unroll
  for (int r = 0; r < 4; ++r) { m_i[r] = -1e30f; l_i[r] = 0.f; }
#pragma unroll
  for (int jd = 0; jd < 4; ++jd) O[jd] = (f32x4){0.f, 0.f, 0.f, 0.f};

  // V staging indices (bf16 copy, transpose scatter)
  const int vkey = t >> 2;
  const int vdb  = (t & 3) * 16;

  const int nkt = qt + 1;                   // causal: keys <= qb+63
  for (int kt = 0; kt < nkt; ++kt) {
    const int kb = kt * 64;
    __syncthreads();                        // prev tile's fragment reads done

    // ---- K hi/lo via glds, source pre-swizzled to match sw() layout ----
    {
      const short* gkh = qkvh + (rowBase + kb) * K3 + DIM + h * DH;
      const short* gkl = qkvl + (rowBase + kb) * K3 + DIM + h * DH;
#pragma unroll
      for (int it = 0; it < 2; ++it) {
        const int row = wv * 16 + it * 8 + (lane >> 3);
        const int blk = ((lane & 7) ^ row) & 7;
        const size_t go = (size_t)row * K3 + blk * 8;
        glds16(gkh + go, Kh + (wv * 16 + it * 8) * 64);
        glds16(gkl + go, Kl + (wv * 16 + it * 8) * 64);
      }
      // ---- V: bf16 load + transpose scatter into swizzled Vt[d][key] ----
      const short* gv = qkvh + (rowBase + kb + vkey) * K3 + 2 * DIM + h * DH + vdb;
      const bf16x8 v0 = *(const bf16x8*)gv;
      const bf16x8 v1 = *(const bf16x8*)(gv + 8);
#pragma unroll
      for (int e = 0; e < 8; ++e) {
        Vt[sw(vdb + e, vkey)]     = v0[e];
        Vt[sw(vdb + 8 + e, vkey)] = v1[e];
      }
    }
    __syncthreads();                        // staging visible (vmcnt+lgkm drained)

    // ---- S = Q K^T, 4 n-tiles of 16 keys, split-bf16 (hh + hl + lh) ----
    f32x4 s[4];
#pragma unroll
    for (int j = 0; j < 4; ++j) s[j] = (f32x4){0.f, 0.f, 0.f, 0.f};
#pragma unroll
    for (int j = 0; j < 4; ++j) {
#pragma unroll
      for (int ks = 0; ks < 2; ++ks) {
        const bf16x8 kh = *(const bf16x8*)(Kh + sw(16 * j + l15, ks * 32 + quad * 8));
        const bf16x8 kl = *(const bf16x8*)(Kl + sw(16 * j + l15, ks * 32 + quad * 8));
        s[j] = __builtin_amdgcn_mfma_f32_16x16x32_bf16(qah[ks], kh, s[j], 0, 0, 0);
        s[j] = __builtin_amdgcn_mfma_f32_16x16x32_bf16(qal[ks], kh, s[j], 0, 0, 0);
        s[j] = __builtin_amdgcn_mfma_f32_16x16x32_bf16(qah[ks], kl, s[j], 0, 0, 0);
      }
    }

    // ---- scale, causal mask, online softmax (C-layout registers) ----
    const int qrow0 = qb + 16 * wv + 4 * quad;
    float p[4][4];
    float mt[4] = {-1e30f, -1e30f, -1e30f, -1e30f};
#pragma unroll
    for (int j = 0; j < 4; ++j) {
      const int key = kb + 16 * j + l15;
#pragma unroll
      for (int r = 0; r < 4; ++r) {
        float sv = s[j][r] * SCALE;
        if (key > qrow0 + r) sv = NEGV;
        p[j][r] = sv;
        mt[r] = fmaxf(mt[r], sv);
      }
    }
#pragma unroll
    for (int r = 0; r < 4; ++r) {
      mt[r] = fmaxf(mt[r], __shfl_xor(mt[r], 1));
      mt[r] = fmaxf(mt[r], __shfl_xor(mt[r], 2));
      mt[r] = fmaxf(mt[r], __shfl_xor(mt[r], 4));
      mt[r] = fmaxf(mt[r], __shfl_xor(mt[r], 8));
    }
    float alpha[4];
#pragma unroll
    for (int r = 0; r < 4; ++r) {
      const float mn = fmaxf(m_i[r], mt[r]);
      alpha[r] = __expf(m_i[r] - mn);
      m_i[r] = mn;
    }
    float ls[4] = {0.f, 0.f, 0.f, 0.f};
#pragma unroll
    for (int j = 0; j < 4; ++j)
#pragma unroll
      for (int r = 0; r < 4; ++r) {
        p[j][r] = __expf(p[j][r] - m_i[r]);
        ls[r] += p[j][r];
      }
#pragma unroll
    for (int r = 0; r < 4; ++r) {
      ls[r] += __shfl_xor(ls[r], 1);
      ls[r] += __shfl_xor(ls[r], 2);
      ls[r] += __shfl_xor(ls[r], 4);
      ls[r] += __shfl_xor(ls[r], 8);
      l_i[r] = l_i[r] * alpha[r] + ls[r];
    }
#pragma unroll
    for (int jd = 0; jd < 4; ++jd)
#pragma unroll
      for (int r = 0; r < 4; ++r) O[jd][r] *= alpha[r];

    // ---- P (C-layout) -> per-wave LDS (swizzled row-major 16x64) ----
#pragma unroll
    for (int j = 0; j < 4; ++j)
#pragma unroll
      for (int r = 0; r < 4; ++r)
        Ps[wv][sw(4 * quad + r, 16 * j + l15)] = f2bf(p[j][r]);
    __syncthreads();                        // P visible (conservative)

    // ---- O += P V : A = P (A-layout reload), B = Vt (transposed V) ----
#pragma unroll
    for (int ks = 0; ks < 2; ++ks) {
      const bf16x8 pa = *(const bf16x8*)(&Ps[wv][sw(l15, ks * 32 + quad * 8)]);
#pragma unroll
      for (int jd = 0; jd < 4; ++jd) {
        const bf16x8 vb = *(const bf16x8*)(Vt + sw(16 * jd + l15, ks * 32 + quad * 8));
        O[jd] = __builtin_amdgcn_mfma_f32_16x16x32_bf16(pa, vb, O[jd], 0, 0, 0);
      }
    }
  }

  // epilogue: O/l -> bf16 attn ws (C-layout scatter, once per block)
#pragma unroll
  for (int jd = 0; jd < 4; ++jd) {
#pragma unroll
    for (int r = 0; r < 4; ++r) {
      const int row = qb + 16 * wv + 4 * quad + r;
      attno[(rowBase + row) * DIM + h * DH + 16 * jd + l15] =
          __float2bfloat16(O[jd][r] / l_i[r]);
    }
  }
}

// ---------------------------------------------------------------------------
// Kernel 3 (unchanged): out = attn @ w_out^T + b_out
// ---------------------------------------------------------------------------
__global__ __launch_bounds__(256) void out_gemm(
    const __hip_bfloat16* __restrict__ a,    // (8192, 1024) attn, bf16
    const float* __restrict__ wo,            // (1024, 1024) fp32
    const float* __restrict__ bo,            // (1024) fp32
    float* __restrict__ out)                 // (8192, 1024) fp32
{
  __shared__ short As[128 * 32];
  __shared__ short Bs[128 * 32];

  const int t    = threadIdx.x;
  const int lane = t & 63;
  const int wv   = t >> 6;
  const int Mb   = blockIdx.y * 128;
  const int Nb   = blockIdx.x * 128;
  const int wr   = (wv >> 1) * 64;
  const int wc   = (wv & 1) * 64;
  const int l15  = lane & 15;
  const int lq   = lane >> 4;
  const int srow = wv * 16 + (lane >> 2);
  const int scol = (lane & 3) * 8;

  f32x4 acc[4][4];
#pragma unroll
  for (int i = 0; i < 4; i++)
#pragma unroll
    for (int j = 0; j < 4; j++) acc[i][j] = (f32x4){0.f, 0.f, 0.f, 0.f};

  for (int k0 = 0; k0 < DIM; k0 += 32) {
    bf16x8 areg[2], breg[2];
#pragma unroll
    for (int it = 0; it < 2; ++it) {
      areg[it] = *(const bf16x8*)(a + (size_t)(Mb + it * 64 + srow) * DIM + k0 + scol);
      const float* bp = wo + (size_t)(Nb + it * 64 + srow) * DIM + k0 + scol;
      const float4 b0 = *(const float4*)(bp);
      const float4 b1 = *(const float4*)(bp + 4);
      const float bf8[8] = {b0.x, b0.y, b0.z, b0.w, b1.x, b1.y, b1.z, b1.w};
#pragma unroll
      for (int e = 0; e < 8; e++) breg[it][e] = f2bf(bf8[e]);
    }
    __syncthreads();
#pragma unroll
    for (int it = 0; it < 2; ++it) {
      *(bf16x8*)(As + (it * 64 + srow) * 32 + scol) = areg[it];
      *(bf16x8*)(Bs + (it * 64 + srow) * 32 + scol) = breg[it];
    }
    __syncthreads();

    bf16x8 af[4], bfr[4];
#pragma unroll
    for (int i = 0; i < 4; i++)
      af[i] = *(const bf16x8*)(As + (wr + i * 16 + l15) * 32 + lq * 8);
#pragma unroll
    for (int j = 0; j < 4; j++)
      bfr[j] = *(const bf16x8*)(Bs + (wc + j * 16 + l15) * 32 + lq * 8);
#pragma unroll
    for (int i = 0; i < 4; i++)
#pragma unroll
      for (int j = 0; j < 4; j++)
        acc[i][j] = __builtin_amdgcn_mfma_f32_16x16x32_bf16(af[i], bfr[j], acc[i][j], 0, 0, 0);
  }

#pragma unroll
  for (int j = 0; j < 4; j++) {
    const int col = Nb + wc + j * 16 + l15;
    const float bias = bo[col];
#pragma unroll
    for (int i = 0; i < 4; i++) {
#pragma unroll
      for (int r = 0; r < 4; r++) {
        const int row = Mb + wr + i * 16 + lq * 4 + r;
        out[(size_t)row * DIM + col] = acc[i][j][r] + bias;
      }
    }
  }
}

// ---------------------------------------------------------------------------
extern "C" void kernel_launch(void* const* d_in, const int* in_sizes, int n_in,
                              void* d_out, int out_size, void* d_ws, size_t ws_size,
                              hipStream_t stream) {
  const float* q    = (const float*)d_in[0];
  const float* k    = (const float*)d_in[1];
  const float* v    = (const float*)d_in[2];
  const float* wqkv = (const float*)d_in[3];
  const float* bqkv = (const float*)d_in[4];
  const float* wout = (const float*)d_in[5];
  const float* bout = (const float*)d_in[6];

  // ws layout:
  //   [0,48MB)    qkv_hi bf16 (8192x3072)
  //   [48,96MB)   qkv_lo bf16 (8192x3072; only q,k cols written/read)
  //   [96MB,...)  prep path: A_hi(48) A_lo(48) B_hi(18) B_lo(18) = +132MB
  //               attn bf16 (16MB) aliases A_hi (dead after qkv_gemm_pre)
  //   fallback:   attn bf16 at 96MB; total 112MB (prior session's footprint)
  const size_t PLANE = (size_t)MROWS * K3 * 2;        // 50331648 B
  const size_t BPLN  = (size_t)K3 * K3 * 2;           // 18874368 B
  short* qh = (short*)d_ws;
  short* ql = (short*)((char*)d_ws + PLANE);
  char*  p2 = (char*)d_ws + 2 * PLANE;                // offset 96 MB
  __hip_bfloat16* attnws = (__hip_bfloat16*)p2;

  const size_t NEED = 2 * PLANE + 2 * PLANE + 2 * BPLN;  // 228 MB

  if (ws_size >= NEED) {
    short* Ah = (short*)p2;
    short* Al = Ah + (size_t)MROWS * K3;
    short* Bh = Al + (size_t)MROWS * K3;
    short* Bl = Bh + (size_t)K3 * K3;
    prep_x<<<4096, 256, 0, stream>>>(q, k, v, Ah, Al);
    prep_w<<<2048, 256, 0, stream>>>(wqkv, Bh, Bl);
    qkv_gemm_pre<<<dim3(K3 / 128, MROWS / 128), 256, 0, stream>>>(
        Ah, Al, Bh, Bl, bqkv, qh, ql);
  } else {
    qkv_gemm_fly<<<dim3(K3 / 128, MROWS / 128), 256, 0, stream>>>(
        q, k, v, wqkv, bqkv, qh, ql);
  }
  attn_fwd<<<dim3(4 * HEADS * (SEQ / 64)), 256, 0, stream>>>(qh, ql, attnws);
  out_gemm<<<dim3(DIM / 128, MROWS / 128), 256, 0, stream>>>(attnws, wout, bout,
                                                             (float*)d_out);
}

// Round 2
// 846.317 us; speedup vs baseline: 1.1619x; 1.1063x over previous
//
#include <hip/hip_runtime.h>
#include <hip/hip_bf16.h>

// Problem constants: B=4, N=2048, D=1024, H=16, dh=64. All I/O fp32.
#define SEQ   2048
#define DIM   1024
#define HEADS 16
#define DH    64
#define MROWS 8192            // B*N
#define K3    3072            // 3*D
#define NEGV  (-32767.0f)     // -2^15+1, matches reference mask constant
#define SCALE 8.0f            // sqrt(dh) — reference MULTIPLIES by sqrt(d)

typedef __attribute__((ext_vector_type(8))) short bf16x8;
typedef __attribute__((ext_vector_type(4))) float f32x4;

// bf16 round-to-nearest-even via bit ops (finite inputs only)
__device__ __forceinline__ short f2bf(float x) {
  union { float f; unsigned u; } v; v.f = x;
  unsigned r = v.u + 0x7FFF + ((v.u >> 16) & 1);
  return (short)(r >> 16);
}
__device__ __forceinline__ float bf2f(short s) {
  union { float f; unsigned u; } v; v.u = ((unsigned)(unsigned short)s) << 16;
  return v.f;
}
__device__ __forceinline__ void split1(float x, short& h, short& l) {
  h = f2bf(x);
  l = f2bf(x - bf2f(h));
}
__device__ __forceinline__ void cvt_split8(const float4 a, const float4 b,
                                           bf16x8& hi, bf16x8& lo) {
  const float f[8] = {a.x, a.y, a.z, a.w, b.x, b.y, b.z, b.w};
#pragma unroll
  for (int i = 0; i < 8; i++) {
    short h, l; split1(f[i], h, l);
    hi[i] = h; lo[i] = l;
  }
}

// async global->LDS, 16B per lane. LDS dest is wave-uniform base; HW writes
// lane l at base + l*16 bytes. Global src is per-lane.
__device__ __forceinline__ void glds16(const void* g, void* l) {
  __builtin_amdgcn_global_load_lds(
      (const __attribute__((address_space(1))) void*)g,
      (__attribute__((address_space(3))) void*)l, 16, 0, 0);
}

// XOR-swizzled LDS index (shorts) for 64-col row-major tiles: 8-short (16B)
// blocks permuted by row&7 -> ds_read_b128-able fragments, spread banks.
__device__ __forceinline__ int sw(int row, int col) {
  return row * 64 + ((((col >> 3) ^ row) & 7) << 3) + (col & 7);
}

// ---------------------------------------------------------------------------
// Prep kernels: one-time fp32 -> bf16 hi/lo RNE split.
// ---------------------------------------------------------------------------
__global__ __launch_bounds__(256) void prep_x(
    const float* __restrict__ q, const float* __restrict__ k,
    const float* __restrict__ v,
    short* __restrict__ ah, short* __restrict__ al)  // (8192, 3072) bf16 each
{
  const int n = MROWS * (K3 / 4);                    // float4 work items
  for (int i = blockIdx.x * 256 + threadIdx.x; i < n; i += gridDim.x * 256) {
    const int r  = i / 768;                          // 3072/4 cols per row
    const int c4 = i - r * 768;
    const float* src = (c4 < 256) ? q : ((c4 < 512) ? k : v);
    const int cc = c4 & 255;
    const float4 f = *(const float4*)(src + ((size_t)r * 256 + cc) * 4);
    const float fa[4] = {f.x, f.y, f.z, f.w};
    short hi[4], lo[4];
#pragma unroll
    for (int e = 0; e < 4; ++e) split1(fa[e], hi[e], lo[e]);
    const size_t o = (size_t)r * K3 + c4 * 4;
    *(short4*)(ah + o) = make_short4(hi[0], hi[1], hi[2], hi[3]);
    *(short4*)(al + o) = make_short4(lo[0], lo[1], lo[2], lo[3]);
  }
}

__global__ __launch_bounds__(256) void prep_w(
    const float* __restrict__ w,                     // (3072,3072) fp32
    short* __restrict__ bh, short* __restrict__ bl)  // bf16 each
{
  const int n = (K3 * K3) / 4;
  for (int i = blockIdx.x * 256 + threadIdx.x; i < n; i += gridDim.x * 256) {
    const float4 f = ((const float4*)w)[i];
    const float fa[4] = {f.x, f.y, f.z, f.w};
    short hi[4], lo[4];
#pragma unroll
    for (int e = 0; e < 4; ++e) split1(fa[e], hi[e], lo[e]);
    ((short4*)bh)[i] = make_short4(hi[0], hi[1], hi[2], hi[3]);
    ((short4*)bl)[i] = make_short4(lo[0], lo[1], lo[2], lo[3]);
  }
}

// ---------------------------------------------------------------------------
// Kernel 1a: qkv GEMM, 256x256 tile, 8-phase counted-vmcnt schedule (m201
// template). hi/lo compensation folded into K ("packed-K"): q,k col-blocks
// contract K'=9216 = [Ah*Bh | Ah*Bl | Al*Bh]; v col-blocks K'=3072 (Ah*Bh).
// 8 waves (2M x 4N), per-wave C = 128x64. BK=64. LDS = 2buf x {A0,A1,B0,B1}
// halves (128x64 bf16 each, XOR-swizzled via pre-swizzled global source).
//
// Stage schedule (iter j computes tiles 2j in buf0 [P0-3], 2j+1 in buf1
// [P4-7]); B-halves fully read at P0/P4, A-halves by P3/P7:
//   P0: b1.A0 (t+1)   P1: b1.A1 (t+1)   P2: b0.B0 (t+2)  P3: b0.B1 (t+2)
//   P4: b0.A0 (t+2)   P5: b0.A1 (t+2)   P6: b1.B0 (t+3)  P7: b1.B1 (t+3)
// vmcnt(4) at P3 (gates P4-7 reads of buf1: allows P2,P3 = b0.B outstanding)
// and at P7 (gates next P0-3 reads of buf0: allows P6,P7 = b1.B outstanding).
// ---------------------------------------------------------------------------
__device__ __forceinline__ void stage_half(const short* __restrict__ src,
                                           short* dst, int wv, int lane) {
  // half-tile = 128 rows x 64 cols bf16 = 16KB; wave wv covers 2x1KB pieces.
  // LDS dest linear; source col-block pre-swizzled (involution cb^row&7).
#pragma unroll
  for (int e = 0; e < 2; ++e) {
    const int idx = (wv * 2 + e) * 512 + lane * 8;   // linear short index
    const int row = idx >> 6;
    const int cb  = (idx >> 3) & 7;
    const int cbs = (cb ^ row) & 7;
    glds16(src + (size_t)row * K3 + cbs * 8, dst + (wv * 2 + e) * 512);
  }
}

__global__ __launch_bounds__(512, 2) void qkv_gemm_8p(
    const short* __restrict__ Ah, const short* __restrict__ Al,
    const short* __restrict__ Bh, const short* __restrict__ Bl,
    const float* __restrict__ bqkv,
    short* __restrict__ qh, short* __restrict__ ql)
{
  __shared__ short L[2][4][8192];   // [buf][A0,A1,B0,B1][128*64], 128 KB

  const int t    = threadIdx.x;
  const int lane = t & 63;
  const int wv   = t >> 6;          // 0..7
  const int wr   = wv >> 2;         // 0..1  (M: 128-row half)
  const int wc   = wv & 3;          // 0..3  (N: 64-col slice)
  const int l15  = lane & 15;
  const int lq   = lane >> 4;

  // heavy (q,k cols; 144 K-tiles) blocks dispatch first, XCD-chunked.
  int mb, nb;
  {
    const int bx = blockIdx.x;
    if (bx < 256) { const int w = (bx & 7) * 32 + (bx >> 3); mb = w & 31; nb = w >> 5; }
    else { const int i = bx - 256; const int w = (i & 7) * 16 + (i >> 3); mb = w & 31; nb = 8 + (w >> 5); }
  }
  const int Mb = mb * 256;
  const int Nb = nb * 256;
  const bool prec = (Nb < 2 * DIM);
  const int nt = prec ? 144 : 48;   // K-tiles of 64

  // tile kt -> global source for half h (0,1 = A halves; 2,3 = B halves)
  auto tsrc = [&](int kt, int h) -> const short* {
    kt = (kt < nt - 1) ? kt : (nt - 1);
    const int seg = (kt >= 96) ? 2 : ((kt >= 48) ? 1 : 0);
    const int k0  = (kt - seg * 48) * 64;
    if (h < 2) {
      const short* Apl = (seg == 2) ? Al : Ah;
      return Apl + (size_t)(Mb + h * 128) * K3 + k0;
    }
    const short* Bpl = (seg == 1) ? Bl : Bh;
    return Bpl + (size_t)(Nb + (h - 2) * 128) * K3 + k0;
  };

  f32x4 acc[8][4];
#pragma unroll
  for (int i = 0; i < 8; i++)
#pragma unroll
    for (int j = 0; j < 4; j++) acc[i][j] = (f32x4){0.f, 0.f, 0.f, 0.f};

  // prologue: tile 0 -> buf0 (all 4 halves), tile 1 -> buf1 B halves
  stage_half(tsrc(0, 0), &L[0][0][0], wv, lane);
  stage_half(tsrc(0, 1), &L[0][1][0], wv, lane);
  stage_half(tsrc(0, 2), &L[0][2][0], wv, lane);
  stage_half(tsrc(0, 3), &L[0][3][0], wv, lane);
  stage_half(tsrc(1, 2), &L[1][2][0], wv, lane);
  stage_half(tsrc(1, 3), &L[1][3][0], wv, lane);
  asm volatile("s_waitcnt vmcnt(4)" ::: "memory");   // buf0 landed
  __builtin_amdgcn_s_barrier();

  bf16x8 bfr[4][2];                 // B frags, live across each 4-phase group

  for (int kp = 0; kp < nt; kp += 2) {
#pragma unroll
    for (int p = 0; p < 8; ++p) {
      const int buf = p >> 2;
      const int qtr = p & 3;
      const int mi0 = qtr * 2;

      // ---- ds-read this phase's fragments ----
      if (qtr == 0) {
#pragma unroll
        for (int ni = 0; ni < 4; ++ni)
#pragma unroll
          for (int ks = 0; ks < 2; ++ks)
            bfr[ni][ks] = *(const bf16x8*)(
                &L[buf][2 + (wc >> 1)][sw((wc & 1) * 64 + ni * 16 + l15,
                                          ks * 32 + lq * 8)]);
      }
      bf16x8 afr[2][2];
#pragma unroll
      for (int m = 0; m < 2; ++m)
#pragma unroll
        for (int ks = 0; ks < 2; ++ks)
          afr[m][ks] = *(const bf16x8*)(
              &L[buf][wr][sw((mi0 + m) * 16 + l15, ks * 32 + lq * 8)]);

      // ---- stage one half-tile per schedule ----
      {
        const int SB[8] = {1, 1, 0, 0, 0, 0, 1, 1};
        const int SH[8] = {0, 1, 2, 3, 0, 1, 2, 3};
        const int SD[8] = {1, 1, 2, 2, 2, 2, 3, 3};
        stage_half(tsrc(kp + SD[p], SH[p]), &L[SB[p]][SH[p]][0], wv, lane);
      }

      if (qtr == 3) asm volatile("s_waitcnt vmcnt(4)" ::: "memory");
      __builtin_amdgcn_s_barrier();
      asm volatile("s_waitcnt lgkmcnt(0)" ::: "memory");
      __builtin_amdgcn_sched_barrier(0);

      __builtin_amdgcn_s_setprio(1);
#pragma unroll
      for (int m = 0; m < 2; ++m)
#pragma unroll
        for (int ni = 0; ni < 4; ++ni)
#pragma unroll
          for (int ks = 0; ks < 2; ++ks)
            acc[mi0 + m][ni] = __builtin_amdgcn_mfma_f32_16x16x32_bf16(
                afr[m][ks], bfr[ni][ks], acc[mi0 + m][ni], 0, 0, 0);
      __builtin_amdgcn_s_setprio(0);
      __builtin_amdgcn_s_barrier();
    }
  }

  // epilogue: bias + bf16 hi/lo split output
#pragma unroll
  for (int ni = 0; ni < 4; ++ni) {
    const int col = Nb + wc * 64 + ni * 16 + l15;
    const float bias = bqkv[col];
#pragma unroll
    for (int mi = 0; mi < 8; ++mi) {
#pragma unroll
      for (int r = 0; r < 4; ++r) {
        const int row = Mb + wr * 128 + mi * 16 + lq * 4 + r;
        const float xv = acc[mi][ni][r] + bias;
        const short hh = f2bf(xv);
        qh[(size_t)row * K3 + col] = hh;
        if (prec) ql[(size_t)row * K3 + col] = f2bf(xv - bf2f(hh));
      }
    }
  }
}

// ---------------------------------------------------------------------------
// Kernel 1b (fallback, ws too small for prep): in-loop cvt (proven structure),
// epilogue bf16 hi/lo output.
// ---------------------------------------------------------------------------
__global__ __launch_bounds__(256) void qkv_gemm_fly(
    const float* __restrict__ q,
    const float* __restrict__ k,
    const float* __restrict__ v,
    const float* __restrict__ wqkv,
    const float* __restrict__ bqkv,
    short* __restrict__ qh, short* __restrict__ ql)
{
  __shared__ short Ash[128 * 32];
  __shared__ short Asl[128 * 32];
  __shared__ short Bsh[128 * 32];
  __shared__ short Bsl[128 * 32];

  const int t    = threadIdx.x;
  const int lane = t & 63;
  const int wv   = t >> 6;
  const int Mb   = blockIdx.y * 128;
  const int Nb   = blockIdx.x * 128;
  const bool prec = (Nb < 2 * DIM);
  const int wr   = (wv >> 1) * 64;
  const int wc   = (wv & 1) * 64;
  const int l15  = lane & 15;
  const int lq   = lane >> 4;
  const int srow = wv * 16 + (lane >> 2);
  const int scol = (lane & 3) * 8;

  f32x4 acc[4][4];
#pragma unroll
  for (int i = 0; i < 4; i++)
#pragma unroll
    for (int j = 0; j < 4; j++) acc[i][j] = (f32x4){0.f, 0.f, 0.f, 0.f};

  for (int k0 = 0; k0 < K3; k0 += 32) {
    const float* src = (k0 < DIM) ? q : ((k0 < 2 * DIM) ? k : v);
    const int koff = (k0 & (DIM - 1)) + scol;

    bf16x8 ah[2], al[2], bh[2], bl[2];
#pragma unroll
    for (int it = 0; it < 2; ++it) {
      const float* ap = src + (size_t)(Mb + it * 64 + srow) * DIM + koff;
      cvt_split8(*(const float4*)(ap), *(const float4*)(ap + 4), ah[it], al[it]);
      const float* bp = wqkv + (size_t)(Nb + it * 64 + srow) * K3 + k0 + scol;
      cvt_split8(*(const float4*)(bp), *(const float4*)(bp + 4), bh[it], bl[it]);
    }
    __syncthreads();
#pragma unroll
    for (int it = 0; it < 2; ++it) {
      *(bf16x8*)(Ash + (it * 64 + srow) * 32 + scol) = ah[it];
      *(bf16x8*)(Bsh + (it * 64 + srow) * 32 + scol) = bh[it];
      if (prec) {
        *(bf16x8*)(Asl + (it * 64 + srow) * 32 + scol) = al[it];
        *(bf16x8*)(Bsl + (it * 64 + srow) * 32 + scol) = bl[it];
      }
    }
    __syncthreads();

    bf16x8 afh[4], bfh[4];
#pragma unroll
    for (int i = 0; i < 4; i++)
      afh[i] = *(const bf16x8*)(Ash + (wr + i * 16 + l15) * 32 + lq * 8);
#pragma unroll
    for (int j = 0; j < 4; j++)
      bfh[j] = *(const bf16x8*)(Bsh + (wc + j * 16 + l15) * 32 + lq * 8);
#pragma unroll
    for (int i = 0; i < 4; i++)
#pragma unroll
      for (int j = 0; j < 4; j++)
        acc[i][j] = __builtin_amdgcn_mfma_f32_16x16x32_bf16(afh[i], bfh[j], acc[i][j], 0, 0, 0);

    if (prec) {
      bf16x8 afl[4], bfl[4];
#pragma unroll
      for (int i = 0; i < 4; i++)
        afl[i] = *(const bf16x8*)(Asl + (wr + i * 16 + l15) * 32 + lq * 8);
#pragma unroll
      for (int j = 0; j < 4; j++)
        bfl[j] = *(const bf16x8*)(Bsl + (wc + j * 16 + l15) * 32 + lq * 8);
#pragma unroll
      for (int i = 0; i < 4; i++)
#pragma unroll
        for (int j = 0; j < 4; j++) {
          acc[i][j] = __builtin_amdgcn_mfma_f32_16x16x32_bf16(afh[i], bfl[j], acc[i][j], 0, 0, 0);
          acc[i][j] = __builtin_amdgcn_mfma_f32_16x16x32_bf16(afl[i], bfh[j], acc[i][j], 0, 0, 0);
        }
    }
  }

#pragma unroll
  for (int j = 0; j < 4; j++) {
    const int col = Nb + wc + j * 16 + l15;
    const float bias = bqkv[col];
#pragma unroll
    for (int i = 0; i < 4; i++) {
#pragma unroll
      for (int r = 0; r < 4; r++) {
        const int row = Mb + wr + i * 16 + lq * 4 + r;
        const float xv = acc[i][j][r] + bias;
        const short hh = f2bf(xv);
        qh[(size_t)row * K3 + col] = hh;
        if (prec) ql[(size_t)row * K3 + col] = f2bf(xv - bf2f(hh));
      }
    }
  }
}

// ---------------------------------------------------------------------------
// Kernel 2: MFMA flash attention reading bf16 hi/lo qkv planes (unchanged).
// ---------------------------------------------------------------------------
__global__ __launch_bounds__(256) void attn_fwd(
    const short* __restrict__ qkvh,         // (8192, 3072) bf16 hi
    const short* __restrict__ qkvl,         // (8192, 3072) bf16 lo (q,k cols)
    __hip_bfloat16* __restrict__ attno)     // (8192, 1024) bf16
{
  __shared__ short Kh[4096], Kl[4096], Vt[4096];
  __shared__ short Ps[4][1024];             // per-wave 16x64 P tile

  const int bx = blockIdx.x;
  const int qt = 31 - (bx & 31);            // heavy q-tiles dispatch first
  const int h  = (bx >> 5) & 15;
  const int b  = bx >> 9;
  const int qb = qt * 64;

  const int t    = threadIdx.x;
  const int lane = t & 63;
  const int wv   = t >> 6;
  const int l15  = lane & 15;
  const int quad = lane >> 4;
  const size_t rowBase = (size_t)b * SEQ;

  // Q A-fragments: A[m=l15][k=ks*32+quad*8+j], rows qb + 16*wv + l15
  bf16x8 qah[2], qal[2];
  {
    const size_t qoff = (rowBase + qb + 16 * wv + l15) * K3 + h * DH;
#pragma unroll
    for (int ks = 0; ks < 2; ++ks) {
      qah[ks] = *(const bf16x8*)(qkvh + qoff + ks * 32 + quad * 8);
      qal[ks] = *(const bf16x8*)(qkvl + qoff + ks * 32 + quad * 8);
    }
  }

  float m_i[4], l_i[4];
  f32x4 O[4];
#pragma unroll
  for (int r = 0; r < 4; ++r) { m_i[r] = -1e30f; l_i[r] = 0.f; }
#pragma unroll
  for (int jd = 0; jd < 4; ++jd) O[jd] = (f32x4){0.f, 0.f, 0.f, 0.f};

  // V staging indices (bf16 copy, transpose scatter)
  const int vkey = t >> 2;
  const int vdb  = (t & 3) * 16;

  const int nkt = qt + 1;                   // causal: keys <= qb+63
  for (int kt = 0; kt < nkt; ++kt) {
    const int kb = kt * 64;
    __syncthreads();                        // prev tile's fragment reads done

    // ---- K hi/lo via glds, source pre-swizzled to match sw() layout ----
    {
      const short* gkh = qkvh + (rowBase + kb) * K3 + DIM + h * DH;
      const short* gkl = qkvl + (rowBase + kb) * K3 + DIM + h * DH;
#pragma unroll
      for (int it = 0; it < 2; ++it) {
        const int row = wv * 16 + it * 8 + (lane >> 3);
        const int blk = ((lane & 7) ^ row) & 7;
        const size_t go = (size_t)row * K3 + blk * 8;
        glds16(gkh + go, Kh + (wv * 16 + it * 8) * 64);
        glds16(gkl + go, Kl + (wv * 16 + it * 8) * 64);
      }
      // ---- V: bf16 load + transpose scatter into swizzled Vt[d][key] ----
      const short* gv = qkvh + (rowBase + kb + vkey) * K3 + 2 * DIM + h * DH + vdb;
      const bf16x8 v0 = *(const bf16x8*)gv;
      const bf16x8 v1 = *(const bf16x8*)(gv + 8);
#pragma unroll
      for (int e = 0; e < 8; ++e) {
        Vt[sw(vdb + e, vkey)]     = v0[e];
        Vt[sw(vdb + 8 + e, vkey)] = v1[e];
      }
    }
    __syncthreads();                        // staging visible

    // ---- S = Q K^T, 4 n-tiles of 16 keys, split-bf16 (hh + hl + lh) ----
    f32x4 s[4];
#pragma unroll
    for (int j = 0; j < 4; ++j) s[j] = (f32x4){0.f, 0.f, 0.f, 0.f};
#pragma unroll
    for (int j = 0; j < 4; ++j) {
#pragma unroll
      for (int ks = 0; ks < 2; ++ks) {
        const bf16x8 kh = *(const bf16x8*)(Kh + sw(16 * j + l15, ks * 32 + quad * 8));
        const bf16x8 kl = *(const bf16x8*)(Kl + sw(16 * j + l15, ks * 32 + quad * 8));
        s[j] = __builtin_amdgcn_mfma_f32_16x16x32_bf16(qah[ks], kh, s[j], 0, 0, 0);
        s[j] = __builtin_amdgcn_mfma_f32_16x16x32_bf16(qal[ks], kh, s[j], 0, 0, 0);
        s[j] = __builtin_amdgcn_mfma_f32_16x16x32_bf16(qah[ks], kl, s[j], 0, 0, 0);
      }
    }

    // ---- scale, causal mask, online softmax (C-layout registers) ----
    const int qrow0 = qb + 16 * wv + 4 * quad;
    float p[4][4];
    float mt[4] = {-1e30f, -1e30f, -1e30f, -1e30f};
#pragma unroll
    for (int j = 0; j < 4; ++j) {
      const int key = kb + 16 * j + l15;
#pragma unroll
      for (int r = 0; r < 4; ++r) {
        float sv = s[j][r] * SCALE;
        if (key > qrow0 + r) sv = NEGV;
        p[j][r] = sv;
        mt[r] = fmaxf(mt[r], sv);
      }
    }
#pragma unroll
    for (int r = 0; r < 4; ++r) {
      mt[r] = fmaxf(mt[r], __shfl_xor(mt[r], 1));
      mt[r] = fmaxf(mt[r], __shfl_xor(mt[r], 2));
      mt[r] = fmaxf(mt[r], __shfl_xor(mt[r], 4));
      mt[r] = fmaxf(mt[r], __shfl_xor(mt[r], 8));
    }
    float alpha[4];
#pragma unroll
    for (int r = 0; r < 4; ++r) {
      const float mn = fmaxf(m_i[r], mt[r]);
      alpha[r] = __expf(m_i[r] - mn);
      m_i[r] = mn;
    }
    float ls[4] = {0.f, 0.f, 0.f, 0.f};
#pragma unroll
    for (int j = 0; j < 4; ++j)
#pragma unroll
      for (int r = 0; r < 4; ++r) {
        p[j][r] = __expf(p[j][r] - m_i[r]);
        ls[r] += p[j][r];
      }
#pragma unroll
    for (int r = 0; r < 4; ++r) {
      ls[r] += __shfl_xor(ls[r], 1);
      ls[r] += __shfl_xor(ls[r], 2);
      ls[r] += __shfl_xor(ls[r], 4);
      ls[r] += __shfl_xor(ls[r], 8);
      l_i[r] = l_i[r] * alpha[r] + ls[r];
    }
#pragma unroll
    for (int jd = 0; jd < 4; ++jd)
#pragma unroll
      for (int r = 0; r < 4; ++r) O[jd][r] *= alpha[r];

    // ---- P (C-layout) -> per-wave LDS (swizzled row-major 16x64) ----
#pragma unroll
    for (int j = 0; j < 4; ++j)
#pragma unroll
      for (int r = 0; r < 4; ++r)
        Ps[wv][sw(4 * quad + r, 16 * j + l15)] = f2bf(p[j][r]);
    __syncthreads();                        // P visible (conservative)

    // ---- O += P V : A = P (A-layout reload), B = Vt (transposed V) ----
#pragma unroll
    for (int ks = 0; ks < 2; ++ks) {
      const bf16x8 pa = *(const bf16x8*)(&Ps[wv][sw(l15, ks * 32 + quad * 8)]);
#pragma unroll
      for (int jd = 0; jd < 4; ++jd) {
        const bf16x8 vb = *(const bf16x8*)(Vt + sw(16 * jd + l15, ks * 32 + quad * 8));
        O[jd] = __builtin_amdgcn_mfma_f32_16x16x32_bf16(pa, vb, O[jd], 0, 0, 0);
      }
    }
  }

  // epilogue: O/l -> bf16 attn ws (C-layout scatter, once per block)
#pragma unroll
  for (int jd = 0; jd < 4; ++jd) {
#pragma unroll
    for (int r = 0; r < 4; ++r) {
      const int row = qb + 16 * wv + 4 * quad + r;
      attno[(rowBase + row) * DIM + h * DH + 16 * jd + l15] =
          __float2bfloat16(O[jd][r] / l_i[r]);
    }
  }
}

// ---------------------------------------------------------------------------
// Kernel 3 (unchanged): out = attn @ w_out^T + b_out
// ---------------------------------------------------------------------------
__global__ __launch_bounds__(256) void out_gemm(
    const __hip_bfloat16* __restrict__ a,    // (8192, 1024) attn, bf16
    const float* __restrict__ wo,            // (1024, 1024) fp32
    const float* __restrict__ bo,            // (1024) fp32
    float* __restrict__ out)                 // (8192, 1024) fp32
{
  __shared__ short As[128 * 32];
  __shared__ short Bs[128 * 32];

  const int t    = threadIdx.x;
  const int lane = t & 63;
  const int wv   = t >> 6;
  const int Mb   = blockIdx.y * 128;
  const int Nb   = blockIdx.x * 128;
  const int wr   = (wv >> 1) * 64;
  const int wc   = (wv & 1) * 64;
  const int l15  = lane & 15;
  const int lq   = lane >> 4;
  const int srow = wv * 16 + (lane >> 2);
  const int scol = (lane & 3) * 8;

  f32x4 acc[4][4];
#pragma unroll
  for (int i = 0; i < 4; i++)
#pragma unroll
    for (int j = 0; j < 4; j++) acc[i][j] = (f32x4){0.f, 0.f, 0.f, 0.f};

  for (int k0 = 0; k0 < DIM; k0 += 32) {
    bf16x8 areg[2], breg[2];
#pragma unroll
    for (int it = 0; it < 2; ++it) {
      areg[it] = *(const bf16x8*)(a + (size_t)(Mb + it * 64 + srow) * DIM + k0 + scol);
      const float* bp = wo + (size_t)(Nb + it * 64 + srow) * DIM + k0 + scol;
      const float4 b0 = *(const float4*)(bp);
      const float4 b1 = *(const float4*)(bp + 4);
      const float bf8[8] = {b0.x, b0.y, b0.z, b0.w, b1.x, b1.y, b1.z, b1.w};
#pragma unroll
      for (int e = 0; e < 8; e++) breg[it][e] = f2bf(bf8[e]);
    }
    __syncthreads();
#pragma unroll
    for (int it = 0; it < 2; ++it) {
      *(bf16x8*)(As + (it * 64 + srow) * 32 + scol) = areg[it];
      *(bf16x8*)(Bs + (it * 64 + srow) * 32 + scol) = breg[it];
    }
    __syncthreads();

    bf16x8 af[4], bfr[4];
#pragma unroll
    for (int i = 0; i < 4; i++)
      af[i] = *(const bf16x8*)(As + (wr + i * 16 + l15) * 32 + lq * 8);
#pragma unroll
    for (int j = 0; j < 4; j++)
      bfr[j] = *(const bf16x8*)(Bs + (wc + j * 16 + l15) * 32 + lq * 8);
#pragma unroll
    for (int i = 0; i < 4; i++)
#pragma unroll
      for (int j = 0; j < 4; j++)
        acc[i][j] = __builtin_amdgcn_mfma_f32_16x16x32_bf16(af[i], bfr[j], acc[i][j], 0, 0, 0);
  }

#pragma unroll
  for (int j = 0; j < 4; j++) {
    const int col = Nb + wc + j * 16 + l15;
    const float bias = bo[col];
#pragma unroll
    for (int i = 0; i < 4; i++) {
#pragma unroll
      for (int r = 0; r < 4; r++) {
        const int row = Mb + wr + i * 16 + lq * 4 + r;
        out[(size_t)row * DIM + col] = acc[i][j][r] + bias;
      }
    }
  }
}

// ---------------------------------------------------------------------------
extern "C" void kernel_launch(void* const* d_in, const int* in_sizes, int n_in,
                              void* d_out, int out_size, void* d_ws, size_t ws_size,
                              hipStream_t stream) {
  const float* q    = (const float*)d_in[0];
  const float* k    = (const float*)d_in[1];
  const float* v    = (const float*)d_in[2];
  const float* wqkv = (const float*)d_in[3];
  const float* bqkv = (const float*)d_in[4];
  const float* wout = (const float*)d_in[5];
  const float* bout = (const float*)d_in[6];

  // ws layout:
  //   [0,48MB)    qkv_hi bf16 (8192x3072)
  //   [48,96MB)   qkv_lo bf16 (8192x3072; only q,k cols written/read)
  //   [96MB,...)  prep path: A_hi(48) A_lo(48) B_hi(18) B_lo(18) = +132MB
  //               attn bf16 (16MB) aliases A_hi (dead after qkv_gemm_8p)
  //   fallback:   attn bf16 at 96MB
  const size_t PLANE = (size_t)MROWS * K3 * 2;        // 50331648 B
  const size_t BPLN  = (size_t)K3 * K3 * 2;           // 18874368 B
  short* qh = (short*)d_ws;
  short* ql = (short*)((char*)d_ws + PLANE);
  char*  p2 = (char*)d_ws + 2 * PLANE;                // offset 96 MB
  __hip_bfloat16* attnws = (__hip_bfloat16*)p2;

  const size_t NEED = 2 * PLANE + 2 * PLANE + 2 * BPLN;  // 228 MB

  if (ws_size >= NEED) {
    short* Ah = (short*)p2;
    short* Al = Ah + (size_t)MROWS * K3;
    short* Bh = Al + (size_t)MROWS * K3;
    short* Bl = Bh + (size_t)K3 * K3;
    prep_x<<<4096, 256, 0, stream>>>(q, k, v, Ah, Al);
    prep_w<<<2048, 256, 0, stream>>>(wqkv, Bh, Bl);
    qkv_gemm_8p<<<dim3(384), 512, 0, stream>>>(Ah, Al, Bh, Bl, bqkv, qh, ql);
  } else {
    qkv_gemm_fly<<<dim3(K3 / 128, MROWS / 128), 256, 0, stream>>>(
        q, k, v, wqkv, bqkv, qh, ql);
  }
  attn_fwd<<<dim3(4 * HEADS * (SEQ / 64)), 256, 0, stream>>>(qh, ql, attnws);
  out_gemm<<<dim3(DIM / 128, MROWS / 128), 256, 0, stream>>>(attnws, wout, bout,
                                                             (float*)d_out);
}

// Round 3
// 787.677 us; speedup vs baseline: 1.2484x; 1.0744x over previous
//
#include <hip/hip_runtime.h>
#include <hip/hip_bf16.h>

// Problem constants: B=4, N=2048, D=1024, H=16, dh=64. All I/O fp32.
#define SEQ   2048
#define DIM   1024
#define HEADS 16
#define DH    64
#define MROWS 8192            // B*N
#define K3    3072            // 3*D
#define NEGV  (-32767.0f)     // -2^15+1, matches reference mask constant
#define SCALE 8.0f            // sqrt(dh) — reference MULTIPLIES by sqrt(d)

typedef __attribute__((ext_vector_type(8))) short bf16x8;
typedef __attribute__((ext_vector_type(4))) float f32x4;

// bf16 round-to-nearest-even via bit ops (finite inputs only)
__device__ __forceinline__ short f2bf(float x) {
  union { float f; unsigned u; } v; v.f = x;
  unsigned r = v.u + 0x7FFF + ((v.u >> 16) & 1);
  return (short)(r >> 16);
}
__device__ __forceinline__ float bf2f(short s) {
  union { float f; unsigned u; } v; v.u = ((unsigned)(unsigned short)s) << 16;
  return v.f;
}
__device__ __forceinline__ void split1(float x, short& h, short& l) {
  h = f2bf(x);
  l = f2bf(x - bf2f(h));
}
__device__ __forceinline__ void cvt_split8(const float4 a, const float4 b,
                                           bf16x8& hi, bf16x8& lo) {
  const float f[8] = {a.x, a.y, a.z, a.w, b.x, b.y, b.z, b.w};
#pragma unroll
  for (int i = 0; i < 8; i++) {
    short h, l; split1(f[i], h, l);
    hi[i] = h; lo[i] = l;
  }
}

// async global->LDS, 16B per lane. LDS dest is wave-uniform base; HW writes
// lane l at base + l*16 bytes. Global src is per-lane.
__device__ __forceinline__ void glds16(const void* g, void* l) {
  __builtin_amdgcn_global_load_lds(
      (const __attribute__((address_space(1))) void*)g,
      (__attribute__((address_space(3))) void*)l, 16, 0, 0);
}

// XOR-swizzled LDS index (shorts) for 64-col row-major tiles: 8-short (16B)
// blocks permuted by row&7 -> ds_read_b128-able fragments, spread banks.
__device__ __forceinline__ int sw(int row, int col) {
  return row * 64 + ((((col >> 3) ^ row) & 7) << 3) + (col & 7);
}

// ---------------------------------------------------------------------------
// Prep kernels: one-time fp32 -> bf16 hi/lo RNE split.
// ---------------------------------------------------------------------------
__global__ __launch_bounds__(256) void prep_x(
    const float* __restrict__ q, const float* __restrict__ k,
    const float* __restrict__ v,
    short* __restrict__ ah, short* __restrict__ al)  // (8192, 3072) bf16 each
{
  const int n = MROWS * (K3 / 4);                    // float4 work items
  for (int i = blockIdx.x * 256 + threadIdx.x; i < n; i += gridDim.x * 256) {
    const int r  = i / 768;                          // 3072/4 cols per row
    const int c4 = i - r * 768;
    const float* src = (c4 < 256) ? q : ((c4 < 512) ? k : v);
    const int cc = c4 & 255;
    const float4 f = *(const float4*)(src + ((size_t)r * 256 + cc) * 4);
    const float fa[4] = {f.x, f.y, f.z, f.w};
    short hi[4], lo[4];
#pragma unroll
    for (int e = 0; e < 4; ++e) split1(fa[e], hi[e], lo[e]);
    const size_t o = (size_t)r * K3 + c4 * 4;
    *(short4*)(ah + o) = make_short4(hi[0], hi[1], hi[2], hi[3]);
    *(short4*)(al + o) = make_short4(lo[0], lo[1], lo[2], lo[3]);
  }
}

__global__ __launch_bounds__(256) void prep_w(
    const float* __restrict__ w,                     // (3072,3072) fp32
    short* __restrict__ bh, short* __restrict__ bl)  // bf16 each
{
  const int n = (K3 * K3) / 4;
  for (int i = blockIdx.x * 256 + threadIdx.x; i < n; i += gridDim.x * 256) {
    const float4 f = ((const float4*)w)[i];
    const float fa[4] = {f.x, f.y, f.z, f.w};
    short hi[4], lo[4];
#pragma unroll
    for (int e = 0; e < 4; ++e) split1(fa[e], hi[e], lo[e]);
    ((short4*)bh)[i] = make_short4(hi[0], hi[1], hi[2], hi[3]);
    ((short4*)bl)[i] = make_short4(lo[0], lo[1], lo[2], lo[3]);
  }
}

// ---------------------------------------------------------------------------
// Kernel 1a: qkv GEMM, 256x256 tiles, 8-phase counted-vmcnt schedule.
// Grid = 256 blocks; each block computes ONE heavy (q,k cols; packed-K 144
// tiles) 256x256 tile, then HALF of one light (v cols; 48 tiles) 256-wide
// tile (128 rows) -> uniform 168 tile-equivalents per block (load-balanced).
// ---------------------------------------------------------------------------
__device__ __forceinline__ void stage_half(const short* __restrict__ src,
                                           short* dst, int wv, int lane) {
  // half-tile = 128 rows x 64 cols bf16 = 16KB; wave wv covers 2x1KB pieces.
  // LDS dest linear; source col-block pre-swizzled (involution cb^row&7).
#pragma unroll
  for (int e = 0; e < 2; ++e) {
    const int idx = (wv * 2 + e) * 512 + lane * 8;   // linear short index
    const int row = idx >> 6;
    const int cb  = (idx >> 3) & 7;
    const int cbs = (cb ^ row) & 7;
    glds16(src + (size_t)row * K3 + cbs * 8, dst + (wv * 2 + e) * 512);
  }
}

__global__ __launch_bounds__(512, 2) void qkv_gemm_8p(
    const short* __restrict__ Ah, const short* __restrict__ Al,
    const short* __restrict__ Bh, const short* __restrict__ Bl,
    const float* __restrict__ bqkv,
    short* __restrict__ qh, short* __restrict__ ql)
{
  __shared__ short L[2][4][8192];   // [buf][A0,A1,B0,B1][128*64], 128 KB

  const int t    = threadIdx.x;
  const int lane = t & 63;
  const int wv   = t >> 6;          // 0..7
  const int wr   = wv >> 2;         // 0..1  (M half)
  const int wc   = wv & 3;          // 0..3  (N slice)
  const int l15  = lane & 15;
  const int lq   = lane >> 4;

  // ======================= HEAVY: q,k columns =======================
  // XCD-chunked bijective swizzle over 256 heavy tiles (32 M x 8 N).
  const int w  = (blockIdx.x & 7) * 32 + (blockIdx.x >> 3);
  const int Mb = (w & 31) * 256;
  const int Nb = (w >> 5) * 256;    // 0..1792 (q,k cols)
  const int nt = 144;               // packed-K: hh(48) + lh(48... seg map below)

  // tile kt -> source for half h (0,1 = A halves; 2,3 = B halves)
  auto tsrc = [&](int kt, int h) -> const short* {
    kt = (kt < nt - 1) ? kt : (nt - 1);
    const int seg = (kt >= 96) ? 2 : ((kt >= 48) ? 1 : 0);
    const int k0  = (kt - seg * 48) * 64;
    if (h < 2) {
      const short* Apl = (seg == 2) ? Al : Ah;
      return Apl + (size_t)(Mb + h * 128) * K3 + k0;
    }
    const short* Bpl = (seg == 1) ? Bl : Bh;
    return Bpl + (size_t)(Nb + (h - 2) * 128) * K3 + k0;
  };

  f32x4 acc[8][4];
#pragma unroll
  for (int i = 0; i < 8; i++)
#pragma unroll
    for (int j = 0; j < 4; j++) acc[i][j] = (f32x4){0.f, 0.f, 0.f, 0.f};

  // prologue: tile 0 -> buf0 (all 4 halves), tile 1 -> buf1 B halves
  stage_half(tsrc(0, 0), &L[0][0][0], wv, lane);
  stage_half(tsrc(0, 1), &L[0][1][0], wv, lane);
  stage_half(tsrc(0, 2), &L[0][2][0], wv, lane);
  stage_half(tsrc(0, 3), &L[0][3][0], wv, lane);
  stage_half(tsrc(1, 2), &L[1][2][0], wv, lane);
  stage_half(tsrc(1, 3), &L[1][3][0], wv, lane);
  asm volatile("s_waitcnt vmcnt(4)" ::: "memory");   // buf0 landed
  __builtin_amdgcn_s_barrier();

  bf16x8 bfr[4][2];                 // B frags, live across each 4-phase group

  for (int kp = 0; kp < nt; kp += 2) {
#pragma unroll
    for (int p = 0; p < 8; ++p) {
      const int buf = p >> 2;
      const int qtr = p & 3;
      const int mi0 = qtr * 2;

      if (qtr == 0) {
#pragma unroll
        for (int ni = 0; ni < 4; ++ni)
#pragma unroll
          for (int ks = 0; ks < 2; ++ks)
            bfr[ni][ks] = *(const bf16x8*)(
                &L[buf][2 + (wc >> 1)][sw((wc & 1) * 64 + ni * 16 + l15,
                                          ks * 32 + lq * 8)]);
      }
      bf16x8 afr[2][2];
#pragma unroll
      for (int m = 0; m < 2; ++m)
#pragma unroll
        for (int ks = 0; ks < 2; ++ks)
          afr[m][ks] = *(const bf16x8*)(
              &L[buf][wr][sw((mi0 + m) * 16 + l15, ks * 32 + lq * 8)]);

      {
        const int SB[8] = {1, 1, 0, 0, 0, 0, 1, 1};
        const int SH[8] = {0, 1, 2, 3, 0, 1, 2, 3};
        const int SD[8] = {1, 1, 2, 2, 2, 2, 3, 3};
        stage_half(tsrc(kp + SD[p], SH[p]), &L[SB[p]][SH[p]][0], wv, lane);
      }

      if (qtr == 3) asm volatile("s_waitcnt vmcnt(4)" ::: "memory");
      __builtin_amdgcn_s_barrier();
      asm volatile("s_waitcnt lgkmcnt(0)" ::: "memory");
      __builtin_amdgcn_sched_barrier(0);

      __builtin_amdgcn_s_setprio(1);
#pragma unroll
      for (int m = 0; m < 2; ++m)
#pragma unroll
        for (int ni = 0; ni < 4; ++ni)
#pragma unroll
          for (int ks = 0; ks < 2; ++ks)
            acc[mi0 + m][ni] = __builtin_amdgcn_mfma_f32_16x16x32_bf16(
                afr[m][ks], bfr[ni][ks], acc[mi0 + m][ni], 0, 0, 0);
      __builtin_amdgcn_s_setprio(0);
      __builtin_amdgcn_s_barrier();
    }
  }

  // heavy epilogue: bias + bf16 hi/lo split output
#pragma unroll
  for (int ni = 0; ni < 4; ++ni) {
    const int col = Nb + wc * 64 + ni * 16 + l15;
    const float bias = bqkv[col];
#pragma unroll
    for (int mi = 0; mi < 8; ++mi) {
#pragma unroll
      for (int r = 0; r < 4; ++r) {
        const int row = Mb + wr * 128 + mi * 16 + lq * 4 + r;
        const float xv = acc[mi][ni][r] + bias;
        const short hh = f2bf(xv);
        qh[(size_t)row * K3 + col] = hh;
        ql[(size_t)row * K3 + col] = f2bf(xv - bf2f(hh));
      }
    }
  }

  // ======================= LIGHT: v columns (half tile) =======================
  // drain heavy in-flight glds before reusing LDS
  asm volatile("s_waitcnt vmcnt(0)" ::: "memory");
  __builtin_amdgcn_s_barrier();

  const int lt  = blockIdx.x >> 1;                   // 0..127 light tiles
  const int MbL = (lt & 31) * 256 + (blockIdx.x & 1) * 128;
  const int NbL = 2 * DIM + (lt >> 5) * 256;

  auto tsrcL = [&](int kt, int h) -> const short* {
    kt = (kt < 47) ? kt : 47;
    const int k0 = kt * 64;
    if (h == 0) return Ah + (size_t)MbL * K3 + k0;
    return Bh + (size_t)(NbL + (h - 2) * 128) * K3 + k0;
  };

#pragma unroll
  for (int i = 0; i < 4; i++)
#pragma unroll
    for (int j = 0; j < 4; j++) acc[i][j] = (f32x4){0.f, 0.f, 0.f, 0.f};

  // prologue: tile 0 -> buf0 {A,B0,B1}, tile 1 -> buf1 B halves
  stage_half(tsrcL(0, 0), &L[0][0][0], wv, lane);
  stage_half(tsrcL(0, 2), &L[0][2][0], wv, lane);
  stage_half(tsrcL(0, 3), &L[0][3][0], wv, lane);
  stage_half(tsrcL(1, 2), &L[1][2][0], wv, lane);
  stage_half(tsrcL(1, 3), &L[1][3][0], wv, lane);
  asm volatile("s_waitcnt vmcnt(4)" ::: "memory");   // buf0 landed
  __builtin_amdgcn_s_barrier();

  // 4 phases per 2-tile iter; per phase 2 m-frags x 4 n x 2 ks = 16 MFMA.
  for (int kp = 0; kp < 48; kp += 2) {
#pragma unroll
    for (int p = 0; p < 4; ++p) {
      const int buf = p >> 1;
      const int mh  = p & 1;

      if (mh == 0) {
#pragma unroll
        for (int ni = 0; ni < 4; ++ni)
#pragma unroll
          for (int ks = 0; ks < 2; ++ks)
            bfr[ni][ks] = *(const bf16x8*)(
                &L[buf][2 + (wc >> 1)][sw((wc & 1) * 64 + ni * 16 + l15,
                                          ks * 32 + lq * 8)]);
      }
      bf16x8 afr[2][2];
#pragma unroll
      for (int m = 0; m < 2; ++m)
#pragma unroll
        for (int ks = 0; ks < 2; ++ks)
          afr[m][ks] = *(const bf16x8*)(
              &L[buf][0][sw(wr * 64 + (mh * 2 + m) * 16 + l15,
                            ks * 32 + lq * 8)]);

      if (p == 0) {
        stage_half(tsrcL(kp + 1, 0), &L[1][0][0], wv, lane);
      } else if (p == 1) {
        stage_half(tsrcL(kp + 2, 2), &L[0][2][0], wv, lane);
        stage_half(tsrcL(kp + 2, 3), &L[0][3][0], wv, lane);
      } else if (p == 2) {
        stage_half(tsrcL(kp + 2, 0), &L[0][0][0], wv, lane);
      } else {
        stage_half(tsrcL(kp + 3, 2), &L[1][2][0], wv, lane);
        stage_half(tsrcL(kp + 3, 3), &L[1][3][0], wv, lane);
      }

      if (mh == 1) asm volatile("s_waitcnt vmcnt(4)" ::: "memory");
      __builtin_amdgcn_s_barrier();
      asm volatile("s_waitcnt lgkmcnt(0)" ::: "memory");
      __builtin_amdgcn_sched_barrier(0);

      __builtin_amdgcn_s_setprio(1);
#pragma unroll
      for (int m = 0; m < 2; ++m)
#pragma unroll
        for (int ni = 0; ni < 4; ++ni)
#pragma unroll
          for (int ks = 0; ks < 2; ++ks)
            acc[mh * 2 + m][ni] = __builtin_amdgcn_mfma_f32_16x16x32_bf16(
                afr[m][ks], bfr[ni][ks], acc[mh * 2 + m][ni], 0, 0, 0);
      __builtin_amdgcn_s_setprio(0);
      __builtin_amdgcn_s_barrier();
    }
  }

  // light epilogue: bias + bf16 (v cols need no lo plane)
#pragma unroll
  for (int ni = 0; ni < 4; ++ni) {
    const int col = NbL + wc * 64 + ni * 16 + l15;
    const float bias = bqkv[col];
#pragma unroll
    for (int mi = 0; mi < 4; ++mi) {
#pragma unroll
      for (int r = 0; r < 4; ++r) {
        const int row = MbL + wr * 64 + mi * 16 + lq * 4 + r;
        qh[(size_t)row * K3 + col] = f2bf(acc[mi][ni][r] + bias);
      }
    }
  }
}

// ---------------------------------------------------------------------------
// Kernel 1b (fallback, ws too small for prep): in-loop cvt, hi/lo output.
// ---------------------------------------------------------------------------
__global__ __launch_bounds__(256) void qkv_gemm_fly(
    const float* __restrict__ q,
    const float* __restrict__ k,
    const float* __restrict__ v,
    const float* __restrict__ wqkv,
    const float* __restrict__ bqkv,
    short* __restrict__ qh, short* __restrict__ ql)
{
  __shared__ short Ash[128 * 32];
  __shared__ short Asl[128 * 32];
  __shared__ short Bsh[128 * 32];
  __shared__ short Bsl[128 * 32];

  const int t    = threadIdx.x;
  const int lane = t & 63;
  const int wv   = t >> 6;
  const int Mb   = blockIdx.y * 128;
  const int Nb   = blockIdx.x * 128;
  const bool prec = (Nb < 2 * DIM);
  const int wr   = (wv >> 1) * 64;
  const int wc   = (wv & 1) * 64;
  const int l15  = lane & 15;
  const int lq   = lane >> 4;
  const int srow = wv * 16 + (lane >> 2);
  const int scol = (lane & 3) * 8;

  f32x4 acc[4][4];
#pragma unroll
  for (int i = 0; i < 4; i++)
#pragma unroll
    for (int j = 0; j < 4; j++) acc[i][j] = (f32x4){0.f, 0.f, 0.f, 0.f};

  for (int k0 = 0; k0 < K3; k0 += 32) {
    const float* src = (k0 < DIM) ? q : ((k0 < 2 * DIM) ? k : v);
    const int koff = (k0 & (DIM - 1)) + scol;

    bf16x8 ah[2], al[2], bh[2], bl[2];
#pragma unroll
    for (int it = 0; it < 2; ++it) {
      const float* ap = src + (size_t)(Mb + it * 64 + srow) * DIM + koff;
      cvt_split8(*(const float4*)(ap), *(const float4*)(ap + 4), ah[it], al[it]);
      const float* bp = wqkv + (size_t)(Nb + it * 64 + srow) * K3 + k0 + scol;
      cvt_split8(*(const float4*)(bp), *(const float4*)(bp + 4), bh[it], bl[it]);
    }
    __syncthreads();
#pragma unroll
    for (int it = 0; it < 2; ++it) {
      *(bf16x8*)(Ash + (it * 64 + srow) * 32 + scol) = ah[it];
      *(bf16x8*)(Bsh + (it * 64 + srow) * 32 + scol) = bh[it];
      if (prec) {
        *(bf16x8*)(Asl + (it * 64 + srow) * 32 + scol) = al[it];
        *(bf16x8*)(Bsl + (it * 64 + srow) * 32 + scol) = bl[it];
      }
    }
    __syncthreads();

    bf16x8 afh[4], bfh[4];
#pragma unroll
    for (int i = 0; i < 4; i++)
      afh[i] = *(const bf16x8*)(Ash + (wr + i * 16 + l15) * 32 + lq * 8);
#pragma unroll
    for (int j = 0; j < 4; j++)
      bfh[j] = *(const bf16x8*)(Bsh + (wc + j * 16 + l15) * 32 + lq * 8);
#pragma unroll
    for (int i = 0; i < 4; i++)
#pragma unroll
      for (int j = 0; j < 4; j++)
        acc[i][j] = __builtin_amdgcn_mfma_f32_16x16x32_bf16(afh[i], bfh[j], acc[i][j], 0, 0, 0);

    if (prec) {
      bf16x8 afl[4], bfl[4];
#pragma unroll
      for (int i = 0; i < 4; i++)
        afl[i] = *(const bf16x8*)(Asl + (wr + i * 16 + l15) * 32 + lq * 8);
#pragma unroll
      for (int j = 0; j < 4; j++)
        bfl[j] = *(const bf16x8*)(Bsl + (wc + j * 16 + l15) * 32 + lq * 8);
#pragma unroll
      for (int i = 0; i < 4; i++)
#pragma unroll
        for (int j = 0; j < 4; j++) {
          acc[i][j] = __builtin_amdgcn_mfma_f32_16x16x32_bf16(afh[i], bfl[j], acc[i][j], 0, 0, 0);
          acc[i][j] = __builtin_amdgcn_mfma_f32_16x16x32_bf16(afl[i], bfh[j], acc[i][j], 0, 0, 0);
        }
    }
  }

#pragma unroll
  for (int j = 0; j < 4; j++) {
    const int col = Nb + wc + j * 16 + l15;
    const float bias = bqkv[col];
#pragma unroll
    for (int i = 0; i < 4; i++) {
#pragma unroll
      for (int r = 0; r < 4; r++) {
        const int row = Mb + wr + i * 16 + lq * 4 + r;
        const float xv = acc[i][j][r] + bias;
        const short hh = f2bf(xv);
        qh[(size_t)row * K3 + col] = hh;
        if (prec) ql[(size_t)row * K3 + col] = f2bf(xv - bf2f(hh));
      }
    }
  }
}

// ---------------------------------------------------------------------------
// Kernel 2: MFMA flash attention, 128-row q-tiles (8 waves, 512 threads).
// Halves K/V staging per unit MFMA vs 64-row tiles. Per-row math sequence
// identical to previous version (same K-tile order) -> bit-identical output.
// ---------------------------------------------------------------------------
__global__ __launch_bounds__(512) void attn_fwd(
    const short* __restrict__ qkvh,         // (8192, 3072) bf16 hi
    const short* __restrict__ qkvl,         // (8192, 3072) bf16 lo (q,k cols)
    __hip_bfloat16* __restrict__ attno)     // (8192, 1024) bf16
{
  __shared__ short Kh[4096], Kl[4096], Vt[4096];
  __shared__ short Ps[8][1024];             // per-wave 16x64 P tile

  const int bx = blockIdx.x;
  const int qt = 15 - (bx & 15);            // heavy q-tiles dispatch first
  const int h  = (bx >> 4) & 15;
  const int b  = bx >> 8;
  const int qb = qt * 128;

  const int t    = threadIdx.x;
  const int lane = t & 63;
  const int wv   = t >> 6;                  // 0..7
  const int l15  = lane & 15;
  const int quad = lane >> 4;
  const size_t rowBase = (size_t)b * SEQ;

  // Q A-fragments: A[m=l15][k=ks*32+quad*8+j], rows qb + 16*wv + l15
  bf16x8 qah[2], qal[2];
  {
    const size_t qoff = (rowBase + qb + 16 * wv + l15) * K3 + h * DH;
#pragma unroll
    for (int ks = 0; ks < 2; ++ks) {
      qah[ks] = *(const bf16x8*)(qkvh + qoff + ks * 32 + quad * 8);
      qal[ks] = *(const bf16x8*)(qkvl + qoff + ks * 32 + quad * 8);
    }
  }

  float m_i[4], l_i[4];
  f32x4 O[4];
#pragma unroll
  for (int r = 0; r < 4; ++r) { m_i[r] = -1e30f; l_i[r] = 0.f; }
#pragma unroll
  for (int jd = 0; jd < 4; ++jd) O[jd] = (f32x4){0.f, 0.f, 0.f, 0.f};

  // V staging indices (512 threads x 8 shorts = 64x64 tile)
  const int vkey = t >> 3;
  const int vdb  = (t & 7) * 8;

  const int nkt = 2 * qt + 2;               // causal: keys <= qb+127
  for (int kt = 0; kt < nkt; ++kt) {
    const int kb = kt * 64;
    __syncthreads();                        // prev tile's fragment reads done

    // ---- K hi/lo via glds (waves 0-3: hi, 4-7: lo), src pre-swizzled ----
    {
      const short* gk = (wv < 4)
          ? qkvh + (rowBase + kb) * K3 + DIM + h * DH
          : qkvl + (rowBase + kb) * K3 + DIM + h * DH;
      short* Kdst = (wv < 4) ? Kh : Kl;
      const int kw = wv & 3;
#pragma unroll
      for (int it = 0; it < 2; ++it) {
        const int row = kw * 16 + it * 8 + (lane >> 3);
        const int blk = ((lane & 7) ^ row) & 7;
        glds16(gk + (size_t)row * K3 + blk * 8, Kdst + (kw * 16 + it * 8) * 64);
      }
      // ---- V: bf16 load + transpose scatter into swizzled Vt[d][key] ----
      const short* gv = qkvh + (rowBase + kb + vkey) * K3 + 2 * DIM + h * DH + vdb;
      const bf16x8 v0 = *(const bf16x8*)gv;
#pragma unroll
      for (int e = 0; e < 8; ++e) Vt[sw(vdb + e, vkey)] = v0[e];
    }
    __syncthreads();                        // staging visible

    // wave-uniform: does this wave's row range see any of these keys?
    const bool active = (kb <= qb + 16 * wv + 15);

    if (active) {
      // ---- S = Q K^T, 4 n-tiles of 16 keys, split-bf16 (hh + hl + lh) ----
      f32x4 s[4];
#pragma unroll
      for (int j = 0; j < 4; ++j) s[j] = (f32x4){0.f, 0.f, 0.f, 0.f};
#pragma unroll
      for (int j = 0; j < 4; ++j) {
#pragma unroll
        for (int ks = 0; ks < 2; ++ks) {
          const bf16x8 kh = *(const bf16x8*)(Kh + sw(16 * j + l15, ks * 32 + quad * 8));
          const bf16x8 kl = *(const bf16x8*)(Kl + sw(16 * j + l15, ks * 32 + quad * 8));
          s[j] = __builtin_amdgcn_mfma_f32_16x16x32_bf16(qah[ks], kh, s[j], 0, 0, 0);
          s[j] = __builtin_amdgcn_mfma_f32_16x16x32_bf16(qal[ks], kh, s[j], 0, 0, 0);
          s[j] = __builtin_amdgcn_mfma_f32_16x16x32_bf16(qah[ks], kl, s[j], 0, 0, 0);
        }
      }

      // ---- scale, causal mask, online softmax (C-layout registers) ----
      const int qrow0 = qb + 16 * wv + 4 * quad;
      float p[4][4];
      float mt[4] = {-1e30f, -1e30f, -1e30f, -1e30f};
#pragma unroll
      for (int j = 0; j < 4; ++j) {
        const int key = kb + 16 * j + l15;
#pragma unroll
        for (int r = 0; r < 4; ++r) {
          float sv = s[j][r] * SCALE;
          if (key > qrow0 + r) sv = NEGV;
          p[j][r] = sv;
          mt[r] = fmaxf(mt[r], sv);
        }
      }
#pragma unroll
      for (int r = 0; r < 4; ++r) {
        mt[r] = fmaxf(mt[r], __shfl_xor(mt[r], 1));
        mt[r] = fmaxf(mt[r], __shfl_xor(mt[r], 2));
        mt[r] = fmaxf(mt[r], __shfl_xor(mt[r], 4));
        mt[r] = fmaxf(mt[r], __shfl_xor(mt[r], 8));
      }
      float alpha[4];
#pragma unroll
      for (int r = 0; r < 4; ++r) {
        const float mn = fmaxf(m_i[r], mt[r]);
        alpha[r] = __expf(m_i[r] - mn);
        m_i[r] = mn;
      }
      float ls[4] = {0.f, 0.f, 0.f, 0.f};
#pragma unroll
      for (int j = 0; j < 4; ++j)
#pragma unroll
        for (int r = 0; r < 4; ++r) {
          p[j][r] = __expf(p[j][r] - m_i[r]);
          ls[r] += p[j][r];
        }
#pragma unroll
      for (int r = 0; r < 4; ++r) {
        ls[r] += __shfl_xor(ls[r], 1);
        ls[r] += __shfl_xor(ls[r], 2);
        ls[r] += __shfl_xor(ls[r], 4);
        ls[r] += __shfl_xor(ls[r], 8);
        l_i[r] = l_i[r] * alpha[r] + ls[r];
      }
#pragma unroll
      for (int jd = 0; jd < 4; ++jd)
#pragma unroll
        for (int r = 0; r < 4; ++r) O[jd][r] *= alpha[r];

      // ---- P (C-layout) -> per-wave LDS (swizzled row-major 16x64) ----
#pragma unroll
      for (int j = 0; j < 4; ++j)
#pragma unroll
        for (int r = 0; r < 4; ++r)
          Ps[wv][sw(4 * quad + r, 16 * j + l15)] = f2bf(p[j][r]);
    }
    __syncthreads();                        // P visible (conservative)

    if (active) {
      // ---- O += P V : A = P (A-layout reload), B = Vt (transposed V) ----
#pragma unroll
      for (int ks = 0; ks < 2; ++ks) {
        const bf16x8 pa = *(const bf16x8*)(&Ps[wv][sw(l15, ks * 32 + quad * 8)]);
#pragma unroll
        for (int jd = 0; jd < 4; ++jd) {
          const bf16x8 vb = *(const bf16x8*)(Vt + sw(16 * jd + l15, ks * 32 + quad * 8));
          O[jd] = __builtin_amdgcn_mfma_f32_16x16x32_bf16(pa, vb, O[jd], 0, 0, 0);
        }
      }
    }
  }

  // epilogue: O/l -> bf16 attn ws (C-layout scatter, once per block)
#pragma unroll
  for (int jd = 0; jd < 4; ++jd) {
#pragma unroll
    for (int r = 0; r < 4; ++r) {
      const int row = qb + 16 * wv + 4 * quad + r;
      attno[(rowBase + row) * DIM + h * DH + 16 * jd + l15] =
          __float2bfloat16(O[jd][r] / l_i[r]);
    }
  }
}

// ---------------------------------------------------------------------------
// Kernel 3 (unchanged): out = attn @ w_out^T + b_out
// ---------------------------------------------------------------------------
__global__ __launch_bounds__(256) void out_gemm(
    const __hip_bfloat16* __restrict__ a,    // (8192, 1024) attn, bf16
    const float* __restrict__ wo,            // (1024, 1024) fp32
    const float* __restrict__ bo,            // (1024) fp32
    float* __restrict__ out)                 // (8192, 1024) fp32
{
  __shared__ short As[128 * 32];
  __shared__ short Bs[128 * 32];

  const int t    = threadIdx.x;
  const int lane = t & 63;
  const int wv   = t >> 6;
  const int Mb   = blockIdx.y * 128;
  const int Nb   = blockIdx.x * 128;
  const int wr   = (wv >> 1) * 64;
  const int wc   = (wv & 1) * 64;
  const int l15  = lane & 15;
  const int lq   = lane >> 4;
  const int srow = wv * 16 + (lane >> 2);
  const int scol = (lane & 3) * 8;

  f32x4 acc[4][4];
#pragma unroll
  for (int i = 0; i < 4; i++)
#pragma unroll
    for (int j = 0; j < 4; j++) acc[i][j] = (f32x4){0.f, 0.f, 0.f, 0.f};

  for (int k0 = 0; k0 < DIM; k0 += 32) {
    bf16x8 areg[2], breg[2];
#pragma unroll
    for (int it = 0; it < 2; ++it) {
      areg[it] = *(const bf16x8*)(a + (size_t)(Mb + it * 64 + srow) * DIM + k0 + scol);
      const float* bp = wo + (size_t)(Nb + it * 64 + srow) * DIM + k0 + scol;
      const float4 b0 = *(const float4*)(bp);
      const float4 b1 = *(const float4*)(bp + 4);
      const float bf8[8] = {b0.x, b0.y, b0.z, b0.w, b1.x, b1.y, b1.z, b1.w};
#pragma unroll
      for (int e = 0; e < 8; e++) breg[it][e] = f2bf(bf8[e]);
    }
    __syncthreads();
#pragma unroll
    for (int it = 0; it < 2; ++it) {
      *(bf16x8*)(As + (it * 64 + srow) * 32 + scol) = areg[it];
      *(bf16x8*)(Bs + (it * 64 + srow) * 32 + scol) = breg[it];
    }
    __syncthreads();

    bf16x8 af[4], bfr[4];
#pragma unroll
    for (int i = 0; i < 4; i++)
      af[i] = *(const bf16x8*)(As + (wr + i * 16 + l15) * 32 + lq * 8);
#pragma unroll
    for (int j = 0; j < 4; j++)
      bfr[j] = *(const bf16x8*)(Bs + (wc + j * 16 + l15) * 32 + lq * 8);
#pragma unroll
    for (int i = 0; i < 4; i++)
#pragma unroll
      for (int j = 0; j < 4; j++)
        acc[i][j] = __builtin_amdgcn_mfma_f32_16x16x32_bf16(af[i], bfr[j], acc[i][j], 0, 0, 0);
  }

#pragma unroll
  for (int j = 0; j < 4; j++) {
    const int col = Nb + wc + j * 16 + l15;
    const float bias = bo[col];
#pragma unroll
    for (int i = 0; i < 4; i++) {
#pragma unroll
      for (int r = 0; r < 4; r++) {
        const int row = Mb + wr + i * 16 + lq * 4 + r;
        out[(size_t)row * DIM + col] = acc[i][j][r] + bias;
      }
    }
  }
}

// ---------------------------------------------------------------------------
extern "C" void kernel_launch(void* const* d_in, const int* in_sizes, int n_in,
                              void* d_out, int out_size, void* d_ws, size_t ws_size,
                              hipStream_t stream) {
  const float* q    = (const float*)d_in[0];
  const float* k    = (const float*)d_in[1];
  const float* v    = (const float*)d_in[2];
  const float* wqkv = (const float*)d_in[3];
  const float* bqkv = (const float*)d_in[4];
  const float* wout = (const float*)d_in[5];
  const float* bout = (const float*)d_in[6];

  // ws layout:
  //   [0,48MB)    qkv_hi bf16 (8192x3072)
  //   [48,96MB)   qkv_lo bf16 (8192x3072; only q,k cols written/read)
  //   [96MB,...)  prep path: A_hi(48) A_lo(48) B_hi(18) B_lo(18) = +132MB
  //               attn bf16 (16MB) aliases A_hi (dead after qkv_gemm_8p? NO —
  //               light phase reads Ah! attn aliases A_lo instead, dead after
  //               heavy loop... A_lo IS read by heavy loop only; safe: attn
  //               runs after qkv_gemm_8p completes entirely.)
  //   fallback:   attn bf16 at 96MB
  const size_t PLANE = (size_t)MROWS * K3 * 2;        // 50331648 B
  const size_t BPLN  = (size_t)K3 * K3 * 2;           // 18874368 B
  short* qh = (short*)d_ws;
  short* ql = (short*)((char*)d_ws + PLANE);
  char*  p2 = (char*)d_ws + 2 * PLANE;                // offset 96 MB
  __hip_bfloat16* attnws = (__hip_bfloat16*)p2;

  const size_t NEED = 2 * PLANE + 2 * PLANE + 2 * BPLN;  // 228 MB

  if (ws_size >= NEED) {
    short* Ah = (short*)p2;
    short* Al = Ah + (size_t)MROWS * K3;
    short* Bh = Al + (size_t)MROWS * K3;
    short* Bl = Bh + (size_t)K3 * K3;
    prep_x<<<4096, 256, 0, stream>>>(q, k, v, Ah, Al);
    prep_w<<<2048, 256, 0, stream>>>(wqkv, Bh, Bl);
    qkv_gemm_8p<<<dim3(256), 512, 0, stream>>>(Ah, Al, Bh, Bl, bqkv, qh, ql);
  } else {
    qkv_gemm_fly<<<dim3(K3 / 128, MROWS / 128), 256, 0, stream>>>(
        q, k, v, wqkv, bqkv, qh, ql);
  }
  attn_fwd<<<dim3(4 * HEADS * (SEQ / 128)), 512, 0, stream>>>(qh, ql, attnws);
  out_gemm<<<dim3(DIM / 128, MROWS / 128), 256, 0, stream>>>(attnws, wout, bout,
                                                             (float*)d_out);
}